// Round 3
// baseline (900.120 us; speedup 1.0000x reference)
//
#include <hip/hip_runtime.h>
#include <hip/hip_bf16.h>

#define N_NODES 50000
#define N_EDGES 800000
#define CH 64
#define N_GRAPHS 256

// ---------------- zero fill ----------------
__global__ void fill_zero(float* __restrict__ p, int n) {
    int i = blockIdx.x * blockDim.x + threadIdx.x;
    if (i < n) p[i] = 0.0f;
}

// ---------------- degree count (in-degree; +1 self loop added in make_dinv) ----------------
__global__ void deg_count(const int* __restrict__ ei, float* __restrict__ deg) {
    int e = blockIdx.x * blockDim.x + threadIdx.x;
    if (e < N_EDGES) {
        int d = ei[N_EDGES + e];         // dst row (int32)
        atomicAdd(&deg[d], 1.0f);
    }
}

__global__ void make_dinv(float* __restrict__ deg) {
    int i = blockIdx.x * blockDim.x + threadIdx.x;
    if (i < N_NODES) {
        float d = deg[i] + 1.0f;         // + self loop
        deg[i] = rsqrtf(d);
    }
}

// ---------------- 64x64 GEMM: out[n,64] = in[n,64] @ W[64,64] ----------------
// one wave per row; W staged in LDS; row element broadcast via shfl
__global__ void gemm64(const float* __restrict__ in, const float* __restrict__ W,
                       float* __restrict__ out, int n) {
    __shared__ float Ws[64 * 64];
    int tid = threadIdx.x;
    for (int i = tid; i < 64 * 64; i += 256) Ws[i] = W[i];
    __syncthreads();
    int lane = tid & 63;
    int wave = tid >> 6;
    int row = blockIdx.x * 4 + wave;
    if (row >= n) return;
    float xv = in[row * 64 + lane];
    float acc = 0.0f;
#pragma unroll
    for (int k = 0; k < 64; ++k) {
        float a = __shfl(xv, k, 64);
        acc = fmaf(a, Ws[k * 64 + lane], acc);
    }
    out[row * 64 + lane] = acc;
}

// ---------------- edge scatter: acc[dst] += dinv[s]*dinv[d] * xw[src] ----------------
// one wave per edge, lane = channel
__global__ void scatter_edges(const int* __restrict__ ei, const float* __restrict__ dinv,
                              const float* __restrict__ xw, float* __restrict__ acc) {
    int e = blockIdx.x * 4 + (threadIdx.x >> 6);
    int lane = threadIdx.x & 63;
    if (e >= N_EDGES) return;
    int s = ei[e];                     // src (int32)
    int d = ei[N_EDGES + e];           // dst (int32)
    float norm = dinv[s] * dinv[d];
    float v = norm * xw[s * 64 + lane];
    atomicAdd(&acc[d * 64 + lane], v);
}

// ---------------- self-loop + bias (+relu) ----------------
__global__ void fixup(const float* __restrict__ xw, float* __restrict__ acc,
                      const float* __restrict__ bias, const float* __restrict__ dinv,
                      int do_relu) {
    int idx = blockIdx.x * blockDim.x + threadIdx.x;
    if (idx >= N_NODES * CH) return;
    int i = idx >> 6;
    int c = idx & 63;
    float di = dinv[i];
    float v = acc[idx] + xw[idx] * di * di + bias[c];
    if (do_relu) v = fmaxf(v, 0.0f);
    acc[idx] = v;
}

// ---------------- global add pool (accumulate straight into d_out) ----------------
__global__ void pool_k(const float* __restrict__ h, const int* __restrict__ batch,
                       float* __restrict__ pool) {
    int idx = blockIdx.x * blockDim.x + threadIdx.x;
    if (idx >= N_NODES * CH) return;
    int i = idx >> 6;
    int c = idx & 63;
    int g = batch[i];                  // graph id (int32)
    atomicAdd(&pool[g * 64 + c], h[idx]);
}

extern "C" void kernel_launch(void* const* d_in, const int* in_sizes, int n_in,
                              void* d_out, int out_size, void* d_ws, size_t ws_size,
                              hipStream_t stream) {
    const float* x   = (const float*)d_in[0];
    const int* ei    = (const int*)d_in[1];   // int32 [2, N_EDGES]
    const int* batch = (const int*)d_in[2];   // int32 [N_NODES]
    const float* W1  = (const float*)d_in[3];
    const float* b1  = (const float*)d_in[4];
    const float* W2  = (const float*)d_in[5];
    const float* b2  = (const float*)d_in[6];
    const float* W3  = (const float*)d_in[7];
    const float* b3  = (const float*)d_in[8];
    float* out = (float*)d_out;

    // workspace layout (bytes): dinv 200192 | XW 12.8M | ACC 12.8M  (total ~25.9MB)
    char* ws = (char*)d_ws;
    float* dinv = (float*)ws;                                   // 50000 f32
    float* XW   = (float*)(ws + 200192);                        // 3.2M f32
    float* ACC  = (float*)(ws + 200192 + 12800000);             // 3.2M f32

    const int NODE_BLK = (N_NODES + 255) / 256;            // 196
    const int EDGE_BLK = (N_EDGES + 255) / 256;            // 3125
    const int NC_BLK   = (N_NODES * CH + 255) / 256;       // 12500
    const int WAVE_EDGE_BLK = (N_EDGES + 3) / 4;           // 200000

    // degree / dinv (shared across layers)
    fill_zero<<<NODE_BLK, 256, 0, stream>>>(dinv, N_NODES);
    deg_count<<<EDGE_BLK, 256, 0, stream>>>(ei, dinv);
    make_dinv<<<NODE_BLK, 256, 0, stream>>>(dinv);

    // ---- layer 1: x -> H1 in ACC
    gemm64<<<12500, 256, 0, stream>>>(x, W1, XW, N_NODES);
    fill_zero<<<NC_BLK, 256, 0, stream>>>(ACC, N_NODES * CH);
    scatter_edges<<<WAVE_EDGE_BLK, 256, 0, stream>>>(ei, dinv, XW, ACC);
    fixup<<<NC_BLK, 256, 0, stream>>>(XW, ACC, b1, dinv, 1);

    // ---- layer 2: H1(ACC) -> XW -> H2 in ACC
    gemm64<<<12500, 256, 0, stream>>>(ACC, W2, XW, N_NODES);
    fill_zero<<<NC_BLK, 256, 0, stream>>>(ACC, N_NODES * CH);
    scatter_edges<<<WAVE_EDGE_BLK, 256, 0, stream>>>(ei, dinv, XW, ACC);
    fixup<<<NC_BLK, 256, 0, stream>>>(XW, ACC, b2, dinv, 1);

    // ---- layer 3: H2(ACC) -> XW -> H3 in ACC (no relu)
    gemm64<<<12500, 256, 0, stream>>>(ACC, W3, XW, N_NODES);
    fill_zero<<<NC_BLK, 256, 0, stream>>>(ACC, N_NODES * CH);
    scatter_edges<<<WAVE_EDGE_BLK, 256, 0, stream>>>(ei, dinv, XW, ACC);
    fixup<<<NC_BLK, 256, 0, stream>>>(XW, ACC, b3, dinv, 0);

    // ---- pool straight into d_out (must overwrite poison -> zero first)
    fill_zero<<<(N_GRAPHS * CH + 255) / 256, 256, 0, stream>>>(out, N_GRAPHS * CH);
    pool_k<<<NC_BLK, 256, 0, stream>>>(ACC, batch, out);
}

// Round 4
// 564.271 us; speedup vs baseline: 1.5952x; 1.5952x over previous
//
#include <hip/hip_runtime.h>
#include <hip/hip_bf16.h>

#define N_NODES 50000
#define N_EDGES 800000
#define CH 64
#define N_GRAPHS 256
#define SCAN_BLOCKS ((N_NODES + 255) / 256)   // 196

// ---------------- zero fills ----------------
__global__ void fill_zero_f(float* __restrict__ p, int n) {
    int i = blockIdx.x * blockDim.x + threadIdx.x;
    if (i < n) p[i] = 0.0f;
}
__global__ void fill_zero_i(int* __restrict__ p, int n) {
    int i = blockIdx.x * blockDim.x + threadIdx.x;
    if (i < n) p[i] = 0;
}

// ---------------- degree count (int, in-degree; +1 self loop later) ----------------
__global__ void deg_count(const int* __restrict__ ei, int* __restrict__ deg) {
    int e = blockIdx.x * blockDim.x + threadIdx.x;
    if (e < N_EDGES) atomicAdd(&deg[ei[N_EDGES + e]], 1);
}

// ---------------- exclusive scan of deg -> rowp (3 kernels) ----------------
__global__ void scan_block(const int* __restrict__ deg, int* __restrict__ rowp,
                           int* __restrict__ bsum) {
    __shared__ int s[256];
    int tid = threadIdx.x;
    int i = blockIdx.x * 256 + tid;
    int v = (i < N_NODES) ? deg[i] : 0;
    s[tid] = v;
    __syncthreads();
    // inclusive scan ladder
    for (int off = 1; off < 256; off <<= 1) {
        int t = (tid >= off) ? s[tid - off] : 0;
        __syncthreads();
        s[tid] += t;
        __syncthreads();
    }
    if (i < N_NODES) rowp[i] = s[tid] - v;     // exclusive
    if (tid == 255) bsum[blockIdx.x] = s[255];
}
__global__ void scan_bsum(int* __restrict__ bsum) {
    if (threadIdx.x == 0 && blockIdx.x == 0) {
        int acc = 0;
        for (int i = 0; i < SCAN_BLOCKS; ++i) { int v = bsum[i]; bsum[i] = acc; acc += v; }
    }
}
__global__ void scan_add(int* __restrict__ rowp, const int* __restrict__ bsum) {
    int i = blockIdx.x * 256 + threadIdx.x;
    if (i < N_NODES) rowp[i] += bsum[blockIdx.x];
}

// ---------------- dinv = rsqrt(deg+1) ----------------
__global__ void make_dinv(const int* __restrict__ deg, float* __restrict__ dinv) {
    int i = blockIdx.x * blockDim.x + threadIdx.x;
    if (i < N_NODES) dinv[i] = rsqrtf((float)deg[i] + 1.0f);
}

// ---------------- CSR fill: col[rowp[d] + cur[d]++] = s ----------------
__global__ void fill_csr(const int* __restrict__ ei, const int* __restrict__ rowp,
                         int* __restrict__ cur, int* __restrict__ col) {
    int e = blockIdx.x * blockDim.x + threadIdx.x;
    if (e >= N_EDGES) return;
    int s = ei[e];
    int d = ei[N_EDGES + e];
    int pos = rowp[d] + atomicAdd(&cur[d], 1);
    col[pos] = s;
}

// ---------------- 64x64 GEMM: out[n,64] = in[n,64] @ W[64,64] ----------------
__global__ void gemm64(const float* __restrict__ in, const float* __restrict__ W,
                       float* __restrict__ out, int n) {
    __shared__ float Ws[64 * 64];
    int tid = threadIdx.x;
    for (int i = tid; i < 64 * 64; i += 256) Ws[i] = W[i];
    __syncthreads();
    int lane = tid & 63;
    int wave = tid >> 6;
    int row = blockIdx.x * 4 + wave;
    if (row >= n) return;
    float xv = in[row * 64 + lane];
    float acc = 0.0f;
#pragma unroll
    for (int k = 0; k < 64; ++k) {
        float a = __shfl(xv, k, 64);
        acc = fmaf(a, Ws[k * 64 + lane], acc);
    }
    out[row * 64 + lane] = acc;
}

// ---------------- fused aggregation: gather CSR + self loop + bias (+relu) ----------------
// one wave per dst node, lane = channel; zero atomics, writes once
__global__ void agg_csr(const int* __restrict__ rowp, const int* __restrict__ deg,
                        const int* __restrict__ col, const float* __restrict__ dinv,
                        const float* __restrict__ xw, const float* __restrict__ bias,
                        float* __restrict__ out, int do_relu) {
    int node = blockIdx.x * 4 + (threadIdx.x >> 6);
    int lane = threadIdx.x & 63;
    if (node >= N_NODES) return;
    float dd = dinv[node];
    int start = rowp[node];
    int cnt = deg[node];
    float acc = xw[node * 64 + lane] * dd * dd;      // self loop
    for (int j = 0; j < cnt; ++j) {
        int s = col[start + j];                       // uniform -> broadcast load
        float nrm = dinv[s] * dd;
        acc = fmaf(nrm, xw[s * 64 + lane], acc);
    }
    acc += bias[lane];
    if (do_relu) acc = fmaxf(acc, 0.0f);
    out[node * 64 + lane] = acc;
}

// ---------------- pool: run-segmented accumulation (batch sorted) ----------------
// block = 256: 4 groups x 64 ch; each group covers 16 consecutive nodes
__global__ void pool_seg(const float* __restrict__ h, const int* __restrict__ batch,
                         float* __restrict__ pool) {
    int ch = threadIdx.x & 63;
    int grp = threadIdx.x >> 6;
    int base = (blockIdx.x * 4 + grp) * 16;
    float acc = 0.0f;
    int curg = -1;
    for (int n = 0; n < 16; ++n) {
        int node = base + n;
        if (node >= N_NODES) break;
        int g = batch[node];
        float v = h[node * 64 + ch];
        if (g != curg) {
            if (curg >= 0) atomicAdd(&pool[curg * 64 + ch], acc);
            curg = g; acc = v;
        } else {
            acc += v;
        }
    }
    if (curg >= 0) atomicAdd(&pool[curg * 64 + ch], acc);
}

extern "C" void kernel_launch(void* const* d_in, const int* in_sizes, int n_in,
                              void* d_out, int out_size, void* d_ws, size_t ws_size,
                              hipStream_t stream) {
    const float* x   = (const float*)d_in[0];
    const int* ei    = (const int*)d_in[1];   // int32 [2, N_EDGES]
    const int* batch = (const int*)d_in[2];   // int32 [N_NODES]
    const float* W1  = (const float*)d_in[3];
    const float* b1  = (const float*)d_in[4];
    const float* W2  = (const float*)d_in[5];
    const float* b2  = (const float*)d_in[6];
    const float* W3  = (const float*)d_in[7];
    const float* b3  = (const float*)d_in[8];
    float* out = (float*)d_out;

    // workspace layout (bytes)
    char* ws = (char*)d_ws;
    float* dinv = (float*)(ws);                       // 50000 f32
    int*   DEG  = (int*)(ws + 200192);                // 50000 i32
    int*   ROWP = (int*)(ws + 400384);                // 50000 i32
    int*   CUR  = (int*)(ws + 600576);                // 50000 i32
    int*   BSUM = (int*)(ws + 800768);                // 196 i32
    int*   COL  = (int*)(ws + 801792);                // 800000 i32
    float* XW   = (float*)(ws + 4001792);             // 3.2M f32
    float* ACC  = (float*)(ws + 16801792);            // 3.2M f32  (end ~29.6MB)

    const int NODE_BLK = (N_NODES + 255) / 256;       // 196
    const int EDGE_BLK = (N_EDGES + 255) / 256;       // 3125
    const int WAVE_NODE_BLK = (N_NODES + 3) / 4;      // 12500

    // ---- CSR build + dinv (shared across layers)
    fill_zero_i<<<NODE_BLK, 256, 0, stream>>>(DEG, N_NODES);
    fill_zero_i<<<NODE_BLK, 256, 0, stream>>>(CUR, N_NODES);
    deg_count<<<EDGE_BLK, 256, 0, stream>>>(ei, DEG);
    scan_block<<<SCAN_BLOCKS, 256, 0, stream>>>(DEG, ROWP, BSUM);
    scan_bsum<<<1, 64, 0, stream>>>(BSUM);
    scan_add<<<SCAN_BLOCKS, 256, 0, stream>>>(ROWP, BSUM);
    make_dinv<<<NODE_BLK, 256, 0, stream>>>(DEG, dinv);
    fill_csr<<<EDGE_BLK, 256, 0, stream>>>(ei, ROWP, CUR, COL);

    // ---- layer 1: x -> H1 in ACC
    gemm64<<<WAVE_NODE_BLK, 256, 0, stream>>>(x, W1, XW, N_NODES);
    agg_csr<<<WAVE_NODE_BLK, 256, 0, stream>>>(ROWP, DEG, COL, dinv, XW, b1, ACC, 1);

    // ---- layer 2: H1(ACC) -> XW -> H2 in ACC
    gemm64<<<WAVE_NODE_BLK, 256, 0, stream>>>(ACC, W2, XW, N_NODES);
    agg_csr<<<WAVE_NODE_BLK, 256, 0, stream>>>(ROWP, DEG, COL, dinv, XW, b2, ACC, 1);

    // ---- layer 3: H2(ACC) -> XW -> H3 in ACC (no relu)
    gemm64<<<WAVE_NODE_BLK, 256, 0, stream>>>(ACC, W3, XW, N_NODES);
    agg_csr<<<WAVE_NODE_BLK, 256, 0, stream>>>(ROWP, DEG, COL, dinv, XW, b3, ACC, 0);

    // ---- pool straight into d_out (poisoned -> zero first)
    fill_zero_f<<<(N_GRAPHS * CH + 255) / 256, 256, 0, stream>>>(out, N_GRAPHS * CH);
    pool_seg<<<(N_NODES + 63) / 64, 256, 0, stream>>>(ACC, batch, out);
}

// Round 5
// 407.675 us; speedup vs baseline: 2.2079x; 1.3841x over previous
//
#include <hip/hip_runtime.h>
#include <hip/hip_bf16.h>

#define N_NODES 50000
#define N_EDGES 800000
#define CH 64
#define N_GRAPHS 256
#define SCAN_BLOCKS ((N_NODES + 255) / 256)   // 196

// ---------------- zero fills ----------------
__global__ void fill_zero_f(float* __restrict__ p, int n) {
    int i = blockIdx.x * blockDim.x + threadIdx.x;
    if (i < n) p[i] = 0.0f;
}
__global__ void fill_zero_i(int* __restrict__ p, int n) {
    int i = blockIdx.x * blockDim.x + threadIdx.x;
    if (i < n) p[i] = 0;
}

// ---------------- degree count (int, in-degree; +1 self loop later) ----------------
__global__ void deg_count(const int* __restrict__ ei, int* __restrict__ deg) {
    int e = blockIdx.x * blockDim.x + threadIdx.x;
    if (e < N_EDGES) atomicAdd(&deg[ei[N_EDGES + e]], 1);
}

// ---------------- exclusive scan of deg -> rowp (3 kernels) ----------------
__global__ void scan_block(const int* __restrict__ deg, int* __restrict__ rowp,
                           int* __restrict__ bsum) {
    __shared__ int s[256];
    int tid = threadIdx.x;
    int i = blockIdx.x * 256 + tid;
    int v = (i < N_NODES) ? deg[i] : 0;
    s[tid] = v;
    __syncthreads();
    for (int off = 1; off < 256; off <<= 1) {
        int t = (tid >= off) ? s[tid - off] : 0;
        __syncthreads();
        s[tid] += t;
        __syncthreads();
    }
    if (i < N_NODES) rowp[i] = s[tid] - v;     // exclusive
    if (tid == 255) bsum[blockIdx.x] = s[255];
}
__global__ void scan_bsum(int* __restrict__ bsum) {
    if (threadIdx.x == 0 && blockIdx.x == 0) {
        int acc = 0;
        for (int i = 0; i < SCAN_BLOCKS; ++i) { int v = bsum[i]; bsum[i] = acc; acc += v; }
    }
}
__global__ void scan_add(int* __restrict__ rowp, const int* __restrict__ bsum) {
    int i = blockIdx.x * 256 + threadIdx.x;
    if (i < N_NODES) rowp[i] += bsum[blockIdx.x];
}

// ---------------- dinv = rsqrt(deg+1) ----------------
__global__ void make_dinv(const int* __restrict__ deg, float* __restrict__ dinv) {
    int i = blockIdx.x * blockDim.x + threadIdx.x;
    if (i < N_NODES) dinv[i] = rsqrtf((float)deg[i] + 1.0f);
}

// ---------------- CSR fill: col[rowp[d] + cur[d]++] = s ----------------
__global__ void fill_csr(const int* __restrict__ ei, const int* __restrict__ rowp,
                         int* __restrict__ cur, int* __restrict__ col) {
    int e = blockIdx.x * blockDim.x + threadIdx.x;
    if (e >= N_EDGES) return;
    int s = ei[e];
    int d = ei[N_EDGES + e];
    int pos = rowp[d] + atomicAdd(&cur[d], 1);
    col[pos] = s;
}

// ---------------- 64x64 GEMM (grid-stride): out[n,64] = in[n,64] @ W[64,64] ----------------
// W staged in LDS once per block; 4 waves x 1 row per iteration
__global__ void gemm64(const float* __restrict__ in, const float* __restrict__ W,
                       float* __restrict__ out, int n) {
    __shared__ float Ws[64 * 64];
    int tid = threadIdx.x;
    for (int i = tid; i < 64 * 64; i += 256) Ws[i] = W[i];
    __syncthreads();
    int lane = tid & 63;
    int wave = tid >> 6;
    for (int row = blockIdx.x * 4 + wave; row < n; row += gridDim.x * 4) {
        float xv = in[row * 64 + lane];
        float acc = 0.0f;
#pragma unroll
        for (int k = 0; k < 64; ++k) {
            float a = __shfl(xv, k, 64);
            acc = fmaf(a, Ws[k * 64 + lane], acc);
        }
        out[row * 64 + lane] = acc;
    }
}

// ---------------- fused aggregation: CSR gather + self loop + bias (+relu) ----------------
// one wave per dst node, lane = channel; unroll x4 for memory-level parallelism
__global__ void agg_csr(const int* __restrict__ rowp, const int* __restrict__ deg,
                        const int* __restrict__ col, const float* __restrict__ dinv,
                        const float* __restrict__ xw, const float* __restrict__ bias,
                        float* __restrict__ out, int do_relu) {
    int node = blockIdx.x * 4 + (threadIdx.x >> 6);
    int lane = threadIdx.x & 63;
    if (node >= N_NODES) return;
    float dd = dinv[node];
    int start = rowp[node];
    int cnt = deg[node];
    float acc0 = xw[node * 64 + lane] * dd * dd;      // self loop
    float acc1 = 0.0f, acc2 = 0.0f, acc3 = 0.0f;
    int j = 0;
    for (; j + 4 <= cnt; j += 4) {
        int s0 = col[start + j + 0];
        int s1 = col[start + j + 1];
        int s2 = col[start + j + 2];
        int s3 = col[start + j + 3];
        float n0 = dinv[s0], n1 = dinv[s1], n2 = dinv[s2], n3 = dinv[s3];
        float x0 = xw[s0 * 64 + lane];
        float x1 = xw[s1 * 64 + lane];
        float x2 = xw[s2 * 64 + lane];
        float x3 = xw[s3 * 64 + lane];
        acc0 = fmaf(n0 * dd, x0, acc0);
        acc1 = fmaf(n1 * dd, x1, acc1);
        acc2 = fmaf(n2 * dd, x2, acc2);
        acc3 = fmaf(n3 * dd, x3, acc3);
    }
    for (; j < cnt; ++j) {
        int s = col[start + j];
        acc0 = fmaf(dinv[s] * dd, xw[s * 64 + lane], acc0);
    }
    float acc = (acc0 + acc1) + (acc2 + acc3) + bias[lane];
    if (do_relu) acc = fmaxf(acc, 0.0f);
    out[node * 64 + lane] = acc;
}

// ---------------- pool: run-segmented accumulation (batch sorted) ----------------
__global__ void pool_seg(const float* __restrict__ h, const int* __restrict__ batch,
                         float* __restrict__ pool) {
    int ch = threadIdx.x & 63;
    int grp = threadIdx.x >> 6;
    int base = (blockIdx.x * 4 + grp) * 16;
    float acc = 0.0f;
    int curg = -1;
    for (int n = 0; n < 16; ++n) {
        int node = base + n;
        if (node >= N_NODES) break;
        int g = batch[node];
        float v = h[node * 64 + ch];
        if (g != curg) {
            if (curg >= 0) atomicAdd(&pool[curg * 64 + ch], acc);
            curg = g; acc = v;
        } else {
            acc += v;
        }
    }
    if (curg >= 0) atomicAdd(&pool[curg * 64 + ch], acc);
}

extern "C" void kernel_launch(void* const* d_in, const int* in_sizes, int n_in,
                              void* d_out, int out_size, void* d_ws, size_t ws_size,
                              hipStream_t stream) {
    const float* x   = (const float*)d_in[0];
    const int* ei    = (const int*)d_in[1];   // int32 [2, N_EDGES]
    const int* batch = (const int*)d_in[2];   // int32 [N_NODES]
    const float* W1  = (const float*)d_in[3];
    const float* b1  = (const float*)d_in[4];
    const float* W2  = (const float*)d_in[5];
    const float* b2  = (const float*)d_in[6];
    const float* W3  = (const float*)d_in[7];
    const float* b3  = (const float*)d_in[8];
    float* out = (float*)d_out;

    // workspace layout (bytes)
    char* ws = (char*)d_ws;
    float* dinv = (float*)(ws);                       // 50000 f32
    int*   DEG  = (int*)(ws + 200192);                // 50048 i32 (padded)
    int*   CUR  = (int*)(ws + 400384);                // 50048 i32 (contiguous w/ DEG)
    int*   ROWP = (int*)(ws + 600576);                // 50000 i32
    int*   BSUM = (int*)(ws + 800768);                // 196 i32
    int*   COL  = (int*)(ws + 801792);                // 800000 i32
    float* XW   = (float*)(ws + 4001792);             // 3.2M f32
    float* ACC  = (float*)(ws + 16801792);            // 3.2M f32  (end ~29.6MB)

    const int NODE_BLK = (N_NODES + 255) / 256;       // 196
    const int EDGE_BLK = (N_EDGES + 255) / 256;       // 3125
    const int WAVE_NODE_BLK = (N_NODES + 3) / 4;      // 12500
    const int GEMM_BLK = 1024;                        // grid-stride; W staged 1024x not 12500x

    // ---- CSR build + dinv (shared across layers)
    fill_zero_i<<<(100096 + 255) / 256, 256, 0, stream>>>(DEG, 100096);  // DEG+CUR contiguous
    deg_count<<<EDGE_BLK, 256, 0, stream>>>(ei, DEG);
    scan_block<<<SCAN_BLOCKS, 256, 0, stream>>>(DEG, ROWP, BSUM);
    scan_bsum<<<1, 64, 0, stream>>>(BSUM);
    scan_add<<<SCAN_BLOCKS, 256, 0, stream>>>(ROWP, BSUM);
    make_dinv<<<NODE_BLK, 256, 0, stream>>>(DEG, dinv);
    fill_csr<<<EDGE_BLK, 256, 0, stream>>>(ei, ROWP, CUR, COL);

    // ---- layer 1: x -> H1 in ACC
    gemm64<<<GEMM_BLK, 256, 0, stream>>>(x, W1, XW, N_NODES);
    agg_csr<<<WAVE_NODE_BLK, 256, 0, stream>>>(ROWP, DEG, COL, dinv, XW, b1, ACC, 1);

    // ---- layer 2: H1(ACC) -> XW -> H2 in ACC
    gemm64<<<GEMM_BLK, 256, 0, stream>>>(ACC, W2, XW, N_NODES);
    agg_csr<<<WAVE_NODE_BLK, 256, 0, stream>>>(ROWP, DEG, COL, dinv, XW, b2, ACC, 1);

    // ---- layer 3: H2(ACC) -> XW -> H3 in ACC (no relu)
    gemm64<<<GEMM_BLK, 256, 0, stream>>>(ACC, W3, XW, N_NODES);
    agg_csr<<<WAVE_NODE_BLK, 256, 0, stream>>>(ROWP, DEG, COL, dinv, XW, b3, ACC, 0);

    // ---- pool straight into d_out (poisoned -> zero first)
    fill_zero_f<<<(N_GRAPHS * CH + 255) / 256, 256, 0, stream>>>(out, N_GRAPHS * CH);
    pool_seg<<<(N_NODES + 63) / 64, 256, 0, stream>>>(ACC, batch, out);
}

// Round 6
// 318.702 us; speedup vs baseline: 2.8243x; 1.2792x over previous
//
#include <hip/hip_runtime.h>
#include <hip/hip_bf16.h>

#define N_NODES 50000
#define N_EDGES 800000
#define CH 64
#define N_GRAPHS 256
#define SCAN_BLOCKS ((N_NODES + 255) / 256)   // 196

// ---------------- zero fills ----------------
__global__ void fill_zero_f(float* __restrict__ p, int n) {
    int i = blockIdx.x * blockDim.x + threadIdx.x;
    if (i < n) p[i] = 0.0f;
}
__global__ void fill_zero_i(int* __restrict__ p, int n) {
    int i = blockIdx.x * blockDim.x + threadIdx.x;
    if (i < n) p[i] = 0;
}

// ---------------- degree count ----------------
__global__ void deg_count(const int* __restrict__ ei, int* __restrict__ deg) {
    int e = blockIdx.x * blockDim.x + threadIdx.x;
    if (e < N_EDGES) atomicAdd(&deg[ei[N_EDGES + e]], 1);
}

// ---------------- scan (+ fused dinv) ----------------
__global__ void scan_block(const int* __restrict__ deg, int* __restrict__ rowp,
                           int* __restrict__ bsum, float* __restrict__ dinv) {
    __shared__ int s[256];
    int tid = threadIdx.x;
    int i = blockIdx.x * 256 + tid;
    int v = (i < N_NODES) ? deg[i] : 0;
    s[tid] = v;
    __syncthreads();
    for (int off = 1; off < 256; off <<= 1) {
        int t = (tid >= off) ? s[tid - off] : 0;
        __syncthreads();
        s[tid] += t;
        __syncthreads();
    }
    if (i < N_NODES) {
        rowp[i] = s[tid] - v;                       // exclusive
        dinv[i] = rsqrtf((float)v + 1.0f);          // + self loop
    }
    if (tid == 255) bsum[blockIdx.x] = s[255];
}
__global__ void scan_bsum(int* __restrict__ bsum) {
    if (threadIdx.x == 0 && blockIdx.x == 0) {
        int acc = 0;
        for (int i = 0; i < SCAN_BLOCKS; ++i) { int v = bsum[i]; bsum[i] = acc; acc += v; }
    }
}
__global__ void scan_add(int* __restrict__ rowp, const int* __restrict__ bsum) {
    int i = blockIdx.x * 256 + threadIdx.x;
    if (i < N_NODES) rowp[i] += bsum[blockIdx.x];
}

// ---------------- CSR fill ----------------
__global__ void fill_csr(const int* __restrict__ ei, const int* __restrict__ rowp,
                         int* __restrict__ cur, int* __restrict__ col) {
    int e = blockIdx.x * blockDim.x + threadIdx.x;
    if (e >= N_EDGES) return;
    int s = ei[e];
    int d = ei[N_EDGES + e];
    int pos = rowp[d] + atomicAdd(&cur[d], 1);
    col[pos] = s;
}

// ---------------- register-blocked GEMM: out[n,64] = in[n,64] @ W[64,64] ----------------
// wave = 8 rows (wave-uniform base -> x loads become scalar s_load_dwordx4);
// W transposed in LDS, stride 68 -> aligned ds_read_b128, conflict-free
__global__ void gemm_reg(const float* __restrict__ in, const float* __restrict__ W,
                         float* __restrict__ out, int n) {
    __shared__ float WT[64 * 68];
    int tid = threadIdx.x;
    for (int i = tid; i < 64 * 64; i += 256) {
        int k = i >> 6, c = i & 63;
        WT[c * 68 + k] = W[i];
    }
    __syncthreads();
    int lane = tid & 63;
    int wv = __builtin_amdgcn_readfirstlane(tid >> 6);   // force wave-uniform
    int row0 = blockIdx.x * 32 + wv * 8;
    if (row0 >= n) return;                               // n % 8 == 0: no straddle
    float acc[8] = {0.f, 0.f, 0.f, 0.f, 0.f, 0.f, 0.f, 0.f};
#pragma unroll 2
    for (int k = 0; k < 64; k += 4) {
        float4 w = *(const float4*)&WT[lane * 68 + k];
#pragma unroll
        for (int r = 0; r < 8; ++r) {
            float4 xv = *(const float4*)&in[(size_t)(row0 + r) * 64 + k]; // scalar load
            acc[r] = fmaf(xv.x, w.x, acc[r]);
            acc[r] = fmaf(xv.y, w.y, acc[r]);
            acc[r] = fmaf(xv.z, w.z, acc[r]);
            acc[r] = fmaf(xv.w, w.w, acc[r]);
        }
    }
#pragma unroll
    for (int r = 0; r < 8; ++r)
        out[(size_t)(row0 + r) * 64 + lane] = acc[r];
}

// ---------------- fused aggregation: CSR gather + self loop + bias (+relu) ----------------
// wave per dst node (scalarized), lane = channel, unroll x8 for MLP
__global__ void agg_csr(const int* __restrict__ rowp, const int* __restrict__ deg,
                        const int* __restrict__ col, const float* __restrict__ dinv,
                        const float* __restrict__ xw, const float* __restrict__ bias,
                        float* __restrict__ out, int do_relu) {
    int wv = __builtin_amdgcn_readfirstlane(threadIdx.x >> 6);
    int node = blockIdx.x * 4 + wv;                      // grid*4 == N_NODES exactly
    int lane = threadIdx.x & 63;
    float dd = dinv[node];
    int start = rowp[node];                              // scalar
    int cnt = deg[node];                                 // scalar
    float acc0 = xw[(size_t)node * 64 + lane] * dd * dd; // self loop
    float acc1 = 0.f, acc2 = 0.f, acc3 = 0.f;
    int j = 0;
    for (; j + 8 <= cnt; j += 8) {
        int s0 = col[start + j + 0], s1 = col[start + j + 1];
        int s2 = col[start + j + 2], s3 = col[start + j + 3];
        int s4 = col[start + j + 4], s5 = col[start + j + 5];
        int s6 = col[start + j + 6], s7 = col[start + j + 7];
        float n0 = dinv[s0], n1 = dinv[s1], n2 = dinv[s2], n3 = dinv[s3];
        float n4 = dinv[s4], n5 = dinv[s5], n6 = dinv[s6], n7 = dinv[s7];
        float x0 = xw[(size_t)s0 * 64 + lane];
        float x1 = xw[(size_t)s1 * 64 + lane];
        float x2 = xw[(size_t)s2 * 64 + lane];
        float x3 = xw[(size_t)s3 * 64 + lane];
        float x4 = xw[(size_t)s4 * 64 + lane];
        float x5 = xw[(size_t)s5 * 64 + lane];
        float x6 = xw[(size_t)s6 * 64 + lane];
        float x7 = xw[(size_t)s7 * 64 + lane];
        acc0 = fmaf(n0 * dd, x0, acc0);
        acc1 = fmaf(n1 * dd, x1, acc1);
        acc2 = fmaf(n2 * dd, x2, acc2);
        acc3 = fmaf(n3 * dd, x3, acc3);
        acc0 = fmaf(n4 * dd, x4, acc0);
        acc1 = fmaf(n5 * dd, x5, acc1);
        acc2 = fmaf(n6 * dd, x6, acc2);
        acc3 = fmaf(n7 * dd, x7, acc3);
    }
    for (; j < cnt; ++j) {
        int s = col[start + j];
        acc0 = fmaf(dinv[s] * dd, xw[(size_t)s * 64 + lane], acc0);
    }
    float acc = (acc0 + acc1) + (acc2 + acc3);
    if (bias) acc += bias[lane];
    if (do_relu) acc = fmaxf(acc, 0.0f);
    out[(size_t)node * 64 + lane] = acc;
}

// ---------------- pool (+ per-graph node count): run-segmented, batch sorted ----------------
__global__ void pool_seg(const float* __restrict__ h, const int* __restrict__ batch,
                         float* __restrict__ pool, float* __restrict__ cntg) {
    int ch = threadIdx.x & 63;
    int grp = threadIdx.x >> 6;
    int base = (blockIdx.x * 4 + grp) * 16;
    float acc = 0.0f;
    int curg = -1, runlen = 0;
    for (int n = 0; n < 16; ++n) {
        int node = base + n;
        if (node >= N_NODES) break;
        int g = batch[node];
        float v = h[(size_t)node * 64 + ch];
        if (g != curg) {
            if (curg >= 0) {
                atomicAdd(&pool[curg * 64 + ch], acc);
                if (ch == 0) atomicAdd(&cntg[curg], (float)runlen);
            }
            curg = g; acc = v; runlen = 1;
        } else { acc += v; runlen++; }
    }
    if (curg >= 0) {
        atomicAdd(&pool[curg * 64 + ch], acc);
        if (ch == 0) atomicAdd(&cntg[curg], (float)runlen);
    }
}

// ---------------- tiny output GEMM: out = P @ W3 + cnt_g * b3 ----------------
__global__ void out_gemm(const float* __restrict__ P, const float* __restrict__ cntg,
                         const float* __restrict__ W, const float* __restrict__ b,
                         float* __restrict__ out) {
    __shared__ float Ws[64 * 64];
    int tid = threadIdx.x;
    for (int i = tid; i < 64 * 64; i += 256) Ws[i] = W[i];
    __syncthreads();
    int lane = tid & 63;
    int g = blockIdx.x * 4 + (tid >> 6);
    if (g >= N_GRAPHS) return;
    float pv = P[g * 64 + lane];
    float acc = 0.0f;
#pragma unroll
    for (int k = 0; k < 64; ++k)
        acc = fmaf(__shfl(pv, k, 64), Ws[k * 64 + lane], acc);
    out[g * 64 + lane] = acc + cntg[g] * b[lane];
}

extern "C" void kernel_launch(void* const* d_in, const int* in_sizes, int n_in,
                              void* d_out, int out_size, void* d_ws, size_t ws_size,
                              hipStream_t stream) {
    const float* x   = (const float*)d_in[0];
    const int* ei    = (const int*)d_in[1];   // int32 [2, N_EDGES]
    const int* batch = (const int*)d_in[2];   // int32 [N_NODES]
    const float* W1  = (const float*)d_in[3];
    const float* b1  = (const float*)d_in[4];
    const float* W2  = (const float*)d_in[5];
    const float* b2  = (const float*)d_in[6];
    const float* W3  = (const float*)d_in[7];
    const float* b3  = (const float*)d_in[8];
    float* out = (float*)d_out;

    // workspace layout (bytes)
    char* ws = (char*)d_ws;
    float* dinv = (float*)(ws);                       // 50000 f32
    int*   DEG  = (int*)(ws + 200192);                // 50048 i32
    int*   CUR  = (int*)(ws + 400384);                // 50048 i32 (contiguous w/ DEG)
    int*   ROWP = (int*)(ws + 600576);                // 50000 i32
    int*   BSUM = (int*)(ws + 800768);                // 196 i32
    int*   COL  = (int*)(ws + 801792);                // 800000 i32
    float* XW   = (float*)(ws + 4001792);             // 3.2M f32
    float* ACC  = (float*)(ws + 16801792);            // 3.2M f32
    float* POOL = (float*)(ws + 29601792);            // 16384 f32
    float* CNT  = (float*)(ws + 29667328);            // 256 f32  (end ~29.7MB)

    const int EDGE_BLK = (N_EDGES + 255) / 256;       // 3125
    const int WAVE_NODE_BLK = N_NODES / 4;            // 12500 (exact)
    const int GEMM_BLK = (N_NODES + 31) / 32;         // 1563

    // ---- CSR build + dinv (shared across layers)
    fill_zero_i<<<(100096 + 255) / 256, 256, 0, stream>>>(DEG, 100096);  // DEG+CUR
    deg_count<<<EDGE_BLK, 256, 0, stream>>>(ei, DEG);
    scan_block<<<SCAN_BLOCKS, 256, 0, stream>>>(DEG, ROWP, BSUM, dinv);
    scan_bsum<<<1, 64, 0, stream>>>(BSUM);
    scan_add<<<SCAN_BLOCKS, 256, 0, stream>>>(ROWP, BSUM);
    fill_csr<<<EDGE_BLK, 256, 0, stream>>>(ei, ROWP, CUR, COL);

    // ---- layer 1: x -> H1 in ACC
    gemm_reg<<<GEMM_BLK, 256, 0, stream>>>(x, W1, XW, N_NODES);
    agg_csr<<<WAVE_NODE_BLK, 256, 0, stream>>>(ROWP, DEG, COL, dinv, XW, b1, ACC, 1);

    // ---- layer 2: H1 -> H2 in ACC
    gemm_reg<<<GEMM_BLK, 256, 0, stream>>>(ACC, W2, XW, N_NODES);
    agg_csr<<<WAVE_NODE_BLK, 256, 0, stream>>>(ROWP, DEG, COL, dinv, XW, b2, ACC, 1);

    // ---- layer 3 (reordered): Z = A_hat H2 -> pool -> small GEMM
    // pool(A_hat H2 W3 + b3) == pool(A_hat H2) @ W3 + cnt_g * b3  (linearity)
    agg_csr<<<WAVE_NODE_BLK, 256, 0, stream>>>(ROWP, DEG, COL, dinv, ACC, nullptr, XW, 0);
    fill_zero_f<<<(16640 + 255) / 256, 256, 0, stream>>>(POOL, 16640);   // POOL+CNT
    pool_seg<<<(N_NODES + 63) / 64, 256, 0, stream>>>(XW, batch, POOL, CNT);
    out_gemm<<<N_GRAPHS / 4, 256, 0, stream>>>(POOL, CNT, W3, b3, out);
}

// Round 7
// 299.613 us; speedup vs baseline: 3.0043x; 1.0637x over previous
//
#include <hip/hip_runtime.h>
#include <hip/hip_bf16.h>

#define N_NODES 50000
#define N_EDGES 800000
#define CH 64
#define N_GRAPHS 256
#define SCAN_BLOCKS ((N_NODES + 255) / 256)   // 196

__device__ __forceinline__ unsigned bf16_rne(float f) {
    unsigned u = __float_as_uint(f);
    return (u + 0x7fffu + ((u >> 16) & 1u)) >> 16;
}
__device__ __forceinline__ float4 ldtab(const unsigned short* __restrict__ tab, int s, int c4) {
    uint2 u = *(const uint2*)(tab + ((size_t)s << 6) + c4);
    float4 r;
    r.x = __uint_as_float(u.x << 16);
    r.y = __uint_as_float(u.x & 0xffff0000u);
    r.z = __uint_as_float(u.y << 16);
    r.w = __uint_as_float(u.y & 0xffff0000u);
    return r;
}

// ---------------- zero fill ----------------
__global__ void fill_zero_i(int* __restrict__ p, int n) {
    int i = blockIdx.x * blockDim.x + threadIdx.x;
    if (i < n) p[i] = 0;
}

// ---------------- degree count: 2 edges/thread ----------------
__global__ void deg_count(const int* __restrict__ ei, int* __restrict__ deg) {
    int e0 = (blockIdx.x * 256 + threadIdx.x) * 2;
    if (e0 >= N_EDGES) return;
    int2 d2 = *(const int2*)&ei[N_EDGES + e0];
    atomicAdd(&deg[d2.x], 1);
    atomicAdd(&deg[d2.y], 1);
}

// ---------------- block scan + dinv + POOL zero ----------------
__global__ void scan_block(const int* __restrict__ deg, int* __restrict__ rowp,
                           int* __restrict__ bsum, float* __restrict__ dinv,
                           float* __restrict__ poolz) {
    __shared__ int s[256];
    int tid = threadIdx.x;
    int i = blockIdx.x * 256 + tid;
    int v = (i < N_NODES) ? deg[i] : 0;
    s[tid] = v;
    __syncthreads();
    for (int off = 1; off < 256; off <<= 1) {
        int t = (tid >= off) ? s[tid - off] : 0;
        __syncthreads();
        s[tid] += t;
        __syncthreads();
    }
    if (i < N_NODES) {
        rowp[i] = s[tid] - v;                       // exclusive
        dinv[i] = rsqrtf((float)v + 1.0f);          // + self loop
    }
    if (tid == 255) bsum[blockIdx.x] = s[255];
    if (i < N_GRAPHS * CH + N_GRAPHS) poolz[i] = 0.0f;   // POOL + CNT zero (16640 floats)
}
// add cross-block prefix (each block sums bsum[0..bid-1]; uniform L2-hit loads)
__global__ void scan_add(int* __restrict__ rowp, const int* __restrict__ bsum) {
    int prefix = 0;
    int nb = blockIdx.x;
    for (int k = 0; k < nb; ++k) prefix += bsum[k];
    int i = blockIdx.x * 256 + threadIdx.x;
    if (i < N_NODES) rowp[i] += prefix;
}

// ---------------- CSR fill: consumes rowp (becomes end-pointers); 2 edges/thread ----------------
__global__ void fill_csr(const int* __restrict__ ei, int* __restrict__ rowp,
                         int* __restrict__ col) {
    int e0 = (blockIdx.x * 256 + threadIdx.x) * 2;
    if (e0 >= N_EDGES) return;
    int2 s2 = *(const int2*)&ei[e0];
    int2 d2 = *(const int2*)&ei[N_EDGES + e0];
    int p0 = atomicAdd(&rowp[d2.x], 1);
    col[p0] = s2.x;
    int p1 = atomicAdd(&rowp[d2.y], 1);
    col[p1] = s2.y;
}

// ---------------- register-blocked GEMM -> bf16 out: out[n,64] = in[n,64] @ W[64,64] ----------------
// wave = 8 rows (wave-uniform base -> scalar x loads); W^T in LDS stride 68
__global__ void gemm_reg(const float* __restrict__ in, const float* __restrict__ W,
                         unsigned short* __restrict__ out, int n) {
    __shared__ float WT[64 * 68];
    int tid = threadIdx.x;
    for (int i = tid; i < 64 * 64; i += 256) {
        int k = i >> 6, c = i & 63;
        WT[c * 68 + k] = W[i];
    }
    __syncthreads();
    int lane = tid & 63;
    int wv = __builtin_amdgcn_readfirstlane(tid >> 6);
    int row0 = blockIdx.x * 32 + wv * 8;
    if (row0 >= n) return;
    float acc[8] = {0.f, 0.f, 0.f, 0.f, 0.f, 0.f, 0.f, 0.f};
#pragma unroll 2
    for (int k = 0; k < 64; k += 4) {
        float4 w = *(const float4*)&WT[lane * 68 + k];
#pragma unroll
        for (int r = 0; r < 8; ++r) {
            float4 xv = *(const float4*)&in[(size_t)(row0 + r) * 64 + k];  // scalar load
            acc[r] = fmaf(xv.x, w.x, acc[r]);
            acc[r] = fmaf(xv.y, w.y, acc[r]);
            acc[r] = fmaf(xv.z, w.z, acc[r]);
            acc[r] = fmaf(xv.w, w.w, acc[r]);
        }
    }
#pragma unroll
    for (int r = 0; r < 8; ++r)
        out[(size_t)(row0 + r) * 64 + lane] = (unsigned short)bf16_rne(acc[r]);
}

// ---------------- fused aggregation, float4-quad form ----------------
// wave = 1 node; lane l: edge slot q=l>>4, channel quad c4=(l&15)*4.
// Each gather instr moves 4 edges x 16B/lane; cross-quad shfl reduction at end.
template <int OUT_BF16>
__global__ void agg_v4(const int* __restrict__ endp, const int* __restrict__ deg,
                       const int* __restrict__ col, const float* __restrict__ dinv,
                       const unsigned short* __restrict__ tab, const float* __restrict__ bias,
                       void* __restrict__ outv, int do_relu) {
    int wv = __builtin_amdgcn_readfirstlane(threadIdx.x >> 6);
    int node = blockIdx.x * 4 + wv;                 // grid*4 == N_NODES exactly
    int lane = threadIdx.x & 63;
    int q = lane >> 4;
    int c4 = (lane & 15) << 2;
    float dd = dinv[node];
    int cnt = deg[node];                            // scalar
    int start = endp[node] - cnt;                   // endp = rowp after fill_csr
    float4 acc = make_float4(0.f, 0.f, 0.f, 0.f);
    if (q == 0) {                                   // self loop once
        float4 xs = ldtab(tab, node, c4);
        float dd2 = dd * dd;
        acc.x = xs.x * dd2; acc.y = xs.y * dd2; acc.z = xs.z * dd2; acc.w = xs.w * dd2;
    }
    int j = 0;
    for (; j + 8 <= cnt; j += 8) {                  // 8 edges in flight (2KB/wave)
        int sA = col[start + j + q];
        int sB = col[start + j + 4 + q];
        float nA = dinv[sA] * dd;
        float nB = dinv[sB] * dd;
        float4 xA = ldtab(tab, sA, c4);
        float4 xB = ldtab(tab, sB, c4);
        acc.x = fmaf(nA, xA.x, acc.x); acc.y = fmaf(nA, xA.y, acc.y);
        acc.z = fmaf(nA, xA.z, acc.z); acc.w = fmaf(nA, xA.w, acc.w);
        acc.x = fmaf(nB, xB.x, acc.x); acc.y = fmaf(nB, xB.y, acc.y);
        acc.z = fmaf(nB, xB.z, acc.z); acc.w = fmaf(nB, xB.w, acc.w);
    }
    for (; j < cnt; j += 4) {                       // predicated tail
        int jj = j + q;
        bool valid = jj < cnt;
        int s = col[start + (valid ? jj : 0)];
        float nv = valid ? dinv[s] * dd : 0.0f;
        float4 xv = ldtab(tab, s, c4);
        acc.x = fmaf(nv, xv.x, acc.x); acc.y = fmaf(nv, xv.y, acc.y);
        acc.z = fmaf(nv, xv.z, acc.z); acc.w = fmaf(nv, xv.w, acc.w);
    }
    // reduce the 4 edge-slot partials (lanes l, l^16, l^32)
    acc.x += __shfl_xor(acc.x, 16); acc.y += __shfl_xor(acc.y, 16);
    acc.z += __shfl_xor(acc.z, 16); acc.w += __shfl_xor(acc.w, 16);
    acc.x += __shfl_xor(acc.x, 32); acc.y += __shfl_xor(acc.y, 32);
    acc.z += __shfl_xor(acc.z, 32); acc.w += __shfl_xor(acc.w, 32);
    if (q == 0) {
        if (bias) {
            float4 bv = *(const float4*)&bias[c4];
            acc.x += bv.x; acc.y += bv.y; acc.z += bv.z; acc.w += bv.w;
        }
        if (do_relu) {
            acc.x = fmaxf(acc.x, 0.f); acc.y = fmaxf(acc.y, 0.f);
            acc.z = fmaxf(acc.z, 0.f); acc.w = fmaxf(acc.w, 0.f);
        }
        if (OUT_BF16) {
            uint2 o;
            o.x = bf16_rne(acc.x) | (bf16_rne(acc.y) << 16);
            o.y = bf16_rne(acc.z) | (bf16_rne(acc.w) << 16);
            *(uint2*)&((unsigned short*)outv)[((size_t)node << 6) + c4] = o;
        } else {
            *(float4*)&((float*)outv)[((size_t)node << 6) + c4] = acc;
        }
    }
}

// ---------------- pool (+ per-graph node count): run-segmented, batch sorted ----------------
__global__ void pool_seg(const float* __restrict__ h, const int* __restrict__ batch,
                         float* __restrict__ pool, float* __restrict__ cntg) {
    int ch = threadIdx.x & 63;
    int grp = threadIdx.x >> 6;
    int base = (blockIdx.x * 4 + grp) * 16;
    float acc = 0.0f;
    int curg = -1, runlen = 0;
    for (int n = 0; n < 16; ++n) {
        int node = base + n;
        if (node >= N_NODES) break;
        int g = batch[node];
        float v = h[((size_t)node << 6) + ch];
        if (g != curg) {
            if (curg >= 0) {
                atomicAdd(&pool[curg * 64 + ch], acc);
                if (ch == 0) atomicAdd(&cntg[curg], (float)runlen);
            }
            curg = g; acc = v; runlen = 1;
        } else { acc += v; runlen++; }
    }
    if (curg >= 0) {
        atomicAdd(&pool[curg * 64 + ch], acc);
        if (ch == 0) atomicAdd(&cntg[curg], (float)runlen);
    }
}

// ---------------- tiny output GEMM: out = P @ W3 + cnt_g * b3 ----------------
__global__ void out_gemm(const float* __restrict__ P, const float* __restrict__ cntg,
                         const float* __restrict__ W, const float* __restrict__ b,
                         float* __restrict__ out) {
    __shared__ float Ws[64 * 64];
    int tid = threadIdx.x;
    for (int i = tid; i < 64 * 64; i += 256) Ws[i] = W[i];
    __syncthreads();
    int lane = tid & 63;
    int g = blockIdx.x * 4 + (tid >> 6);
    if (g >= N_GRAPHS) return;
    float pv = P[g * 64 + lane];
    float acc = 0.0f;
#pragma unroll
    for (int k = 0; k < 64; ++k)
        acc = fmaf(__shfl(pv, k, 64), Ws[k * 64 + lane], acc);
    out[g * 64 + lane] = acc + cntg[g] * b[lane];
}

extern "C" void kernel_launch(void* const* d_in, const int* in_sizes, int n_in,
                              void* d_out, int out_size, void* d_ws, size_t ws_size,
                              hipStream_t stream) {
    const float* x   = (const float*)d_in[0];
    const int* ei    = (const int*)d_in[1];   // int32 [2, N_EDGES]
    const int* batch = (const int*)d_in[2];   // int32 [N_NODES]
    const float* W1  = (const float*)d_in[3];
    const float* b1  = (const float*)d_in[4];
    const float* W2  = (const float*)d_in[5];
    const float* b2  = (const float*)d_in[6];
    const float* W3  = (const float*)d_in[7];
    const float* b3  = (const float*)d_in[8];
    float* out = (float*)d_out;

    // workspace layout (bytes)
    char* ws = (char*)d_ws;
    float* dinv = (float*)(ws);                       // 50000 f32
    int*   DEG  = (int*)(ws + 200192);                // 50048 i32
    int*   ROWP = (int*)(ws + 400384);                // 50000 i32 (endp after fill_csr)
    int*   BSUM = (int*)(ws + 600576);                // 196 i32
    int*   COL  = (int*)(ws + 601600);                // 800000 i32
    float* XW   = (float*)(ws + 3801600);             // 3.2M f32 (also used as bf16 table)
    float* ACC  = (float*)(ws + 16601600);            // 3.2M f32 (H1 f32; later H2 bf16)
    float* POOL = (float*)(ws + 29401600);            // 16384 f32
    float* CNT  = (float*)(ws + 29467136);            // 256 f32 (contiguous after POOL)

    const int HALF_EDGE_BLK = (N_EDGES / 2 + 255) / 256;  // 1563 (2 edges/thread)
    const int WAVE_NODE_BLK = N_NODES / 4;                // 12500 (exact)
    const int GEMM_BLK = (N_NODES + 31) / 32;             // 1563

    // ---- CSR build + dinv (shared across layers)
    fill_zero_i<<<(50048 + 255) / 256, 256, 0, stream>>>(DEG, 50048);
    deg_count<<<HALF_EDGE_BLK, 256, 0, stream>>>(ei, DEG);
    scan_block<<<SCAN_BLOCKS, 256, 0, stream>>>(DEG, ROWP, BSUM, dinv, POOL);
    scan_add<<<SCAN_BLOCKS, 256, 0, stream>>>(ROWP, BSUM);
    fill_csr<<<HALF_EDGE_BLK, 256, 0, stream>>>(ei, ROWP, COL);

    // ---- layer 1: x -> XW(bf16) -> H1(f32) in ACC
    gemm_reg<<<GEMM_BLK, 256, 0, stream>>>(x, W1, (unsigned short*)XW, N_NODES);
    agg_v4<0><<<WAVE_NODE_BLK, 256, 0, stream>>>(ROWP, DEG, COL, dinv,
        (const unsigned short*)XW, b1, ACC, 1);

    // ---- layer 2: H1 -> XW(bf16) -> H2(bf16) in ACC (ACC consumed by gemm first)
    gemm_reg<<<GEMM_BLK, 256, 0, stream>>>(ACC, W2, (unsigned short*)XW, N_NODES);
    agg_v4<1><<<WAVE_NODE_BLK, 256, 0, stream>>>(ROWP, DEG, COL, dinv,
        (const unsigned short*)XW, b2, ACC, 1);

    // ---- layer 3 (reordered): Z = A_hat H2 (f32 in XW) -> pool -> small GEMM
    agg_v4<0><<<WAVE_NODE_BLK, 256, 0, stream>>>(ROWP, DEG, COL, dinv,
        (const unsigned short*)ACC, nullptr, XW, 0);
    pool_seg<<<(N_NODES + 63) / 64, 256, 0, stream>>>(XW, batch, POOL, CNT);
    out_gemm<<<N_GRAPHS / 4, 256, 0, stream>>>(POOL, CNT, W3, b3, out);
}

// Round 8
// 251.717 us; speedup vs baseline: 3.5759x; 1.1903x over previous
//
#include <hip/hip_runtime.h>
#include <hip/hip_bf16.h>

#define N_NODES 50000
#define N_EDGES 800000
#define CH 64
#define N_GRAPHS 256
#define NBUCK 196            // ceil(50000/256); bucket = dst >> 8
#define CHUNK 8192           // edges staged per bin_scatter block

__device__ __forceinline__ unsigned bf16_rne(float f) {
    unsigned u = __float_as_uint(f);
    return (u + 0x7fffu + ((u >> 16) & 1u)) >> 16;
}
__device__ __forceinline__ float4 ldtab(const unsigned short* __restrict__ tab, int s, int c4) {
    uint2 u = *(const uint2*)(tab + ((size_t)s << 6) + c4);
    float4 r;
    r.x = __uint_as_float(u.x << 16);
    r.y = __uint_as_float(u.x & 0xffff0000u);
    r.z = __uint_as_float(u.y << 16);
    r.w = __uint_as_float(u.y & 0xffff0000u);
    return r;
}

// ---------------- tiny zero (ghist) ----------------
__global__ void zero_ghist(int* __restrict__ g) {
    if (threadIdx.x < NBUCK) g[threadIdx.x] = 0;
}

// ---------------- pass A: coarse histogram over dst buckets ----------------
__global__ void edge_hist(const int* __restrict__ ei, int* __restrict__ ghist) {
    __shared__ int h[NBUCK];
    for (int i = threadIdx.x; i < NBUCK; i += 256) h[i] = 0;
    __syncthreads();
    int t = blockIdx.x * 256 + threadIdx.x;
    int stride = gridDim.x * 256 * 4;
    for (int e = t * 4; e < N_EDGES; e += stride) {
        int4 d = *(const int4*)&ei[N_EDGES + e];
        atomicAdd(&h[d.x >> 8], 1);
        atomicAdd(&h[d.y >> 8], 1);
        atomicAdd(&h[d.z >> 8], 1);
        atomicAdd(&h[d.w >> 8], 1);
    }
    __syncthreads();
    for (int i = threadIdx.x; i < NBUCK; i += 256)
        if (h[i]) atomicAdd(&ghist[i], h[i]);
}

// ---------------- pass B: bucket scan (+ POOL/CNT zero) ----------------
__global__ void bucket_scan(const int* __restrict__ ghist, int* __restrict__ bstart,
                            int* __restrict__ gcur, float* __restrict__ poolz) {
    int i = blockIdx.x * 256 + threadIdx.x;
    if (i < N_GRAPHS * CH + N_GRAPHS) poolz[i] = 0.0f;
    if (blockIdx.x != 0) return;
    __shared__ int sc[256];
    int tid = threadIdx.x;
    int v = (tid < NBUCK) ? ghist[tid] : 0;
    sc[tid] = v;
    __syncthreads();
    for (int off = 1; off < 256; off <<= 1) {
        int t = (tid >= off) ? sc[tid - off] : 0;
        __syncthreads();
        sc[tid] += t;
        __syncthreads();
    }
    if (tid < NBUCK) {
        int ex = sc[tid] - v;
        bstart[tid] = ex;
        gcur[tid] = ex;
    }
    if (tid == 255) bstart[NBUCK] = sc[255];   // == N_EDGES
}

// ---------------- pass C: LDS-binned scatter into bucket-sorted EBUF ----------------
// block = 512 threads, 8192 edges; per-bucket contiguous bursts (~42 edges avg)
__global__ __launch_bounds__(512) void bin_scatter(const int* __restrict__ ei,
                                                   int* __restrict__ gcur,
                                                   int2* __restrict__ ebuf) {
    __shared__ int hist[NBUCK];
    __shared__ int lofs[NBUCK];
    __shared__ int gbase[NBUCK];
    __shared__ int cur[NBUCK];
    __shared__ int sc[512];
    __shared__ int2 stage[CHUNK];     // 64KB
    int tid = threadIdx.x;
    for (int i = tid; i < NBUCK; i += 512) hist[i] = 0;
    __syncthreads();
    int e0 = blockIdx.x * CHUNK;
    int n = min(CHUNK, N_EDGES - e0);
    int src[16], dst[16];
#pragma unroll
    for (int k = 0; k < 16; ++k) {
        int idx = k * 512 + tid;
        if (idx < n) {
            int e = e0 + idx;
            src[k] = ei[e];
            dst[k] = ei[N_EDGES + e];
            atomicAdd(&hist[dst[k] >> 8], 1);
        } else dst[k] = -1;
    }
    __syncthreads();
    int v = (tid < NBUCK) ? hist[tid] : 0;
    sc[tid] = v;
    __syncthreads();
    for (int off = 1; off < 512; off <<= 1) {
        int t = (tid >= off) ? sc[tid - off] : 0;
        __syncthreads();
        sc[tid] += t;
        __syncthreads();
    }
    if (tid < NBUCK) {
        int ex = sc[tid] - v;
        lofs[tid] = ex;
        cur[tid] = ex;
        gbase[tid] = v ? atomicAdd(&gcur[tid], v) : 0;
    }
    __syncthreads();
#pragma unroll
    for (int k = 0; k < 16; ++k) {
        if (dst[k] >= 0) {
            int p = atomicAdd(&cur[dst[k] >> 8], 1);
            stage[p] = make_int2(src[k], dst[k]);
        }
    }
    __syncthreads();
    for (int i = tid; i < n; i += 512) {
        int2 p = stage[i];
        int b = p.y >> 8;
        ebuf[gbase[b] + (i - lofs[b])] = p;     // contiguous runs per bucket
    }
}

// ---------------- pass D: per-bucket CSR build (deg, rowp, dinv, col) ----------------
// one block per bucket; all scatter confined to this block's contiguous COL window
__global__ void csr_bucket(const int2* __restrict__ ebuf, const int* __restrict__ bstart,
                           int* __restrict__ deg, int* __restrict__ rowp,
                           float* __restrict__ dinv, int* __restrict__ col) {
    __shared__ int nd[256];
    __shared__ int cur[256];
    __shared__ int sc[256];
    int b = blockIdx.x;
    int tid = threadIdx.x;
    nd[tid] = 0;
    __syncthreads();
    int es = bstart[b], ee = bstart[b + 1];
    for (int e = es + tid; e < ee; e += 256)
        atomicAdd(&nd[ebuf[e].y & 255], 1);
    __syncthreads();
    int v = nd[tid];
    sc[tid] = v;
    __syncthreads();
    for (int off = 1; off < 256; off <<= 1) {
        int t = (tid >= off) ? sc[tid - off] : 0;
        __syncthreads();
        sc[tid] += t;
        __syncthreads();
    }
    int node = b * 256 + tid;
    int lstart = es + sc[tid] - v;
    if (node < N_NODES) {
        deg[node] = v;
        rowp[node] = lstart;
        dinv[node] = rsqrtf((float)v + 1.0f);
    }
    cur[tid] = lstart;
    __syncthreads();
    for (int e = es + tid; e < ee; e += 256) {
        int2 p = ebuf[e];
        int pos = atomicAdd(&cur[p.y & 255], 1);
        col[pos] = p.x;
    }
}

// ---------------- register-blocked GEMM -> bf16 out ----------------
__global__ void gemm_reg(const float* __restrict__ in, const float* __restrict__ W,
                         unsigned short* __restrict__ out, int n) {
    __shared__ float WT[64 * 68];
    int tid = threadIdx.x;
    for (int i = tid; i < 64 * 64; i += 256) {
        int k = i >> 6, c = i & 63;
        WT[c * 68 + k] = W[i];
    }
    __syncthreads();
    int lane = tid & 63;
    int wv = __builtin_amdgcn_readfirstlane(tid >> 6);
    int row0 = blockIdx.x * 32 + wv * 8;
    if (row0 >= n) return;
    float acc[8] = {0.f, 0.f, 0.f, 0.f, 0.f, 0.f, 0.f, 0.f};
#pragma unroll 2
    for (int k = 0; k < 64; k += 4) {
        float4 w = *(const float4*)&WT[lane * 68 + k];
#pragma unroll
        for (int r = 0; r < 8; ++r) {
            float4 xv = *(const float4*)&in[(size_t)(row0 + r) * 64 + k];  // scalar load
            acc[r] = fmaf(xv.x, w.x, acc[r]);
            acc[r] = fmaf(xv.y, w.y, acc[r]);
            acc[r] = fmaf(xv.z, w.z, acc[r]);
            acc[r] = fmaf(xv.w, w.w, acc[r]);
        }
    }
#pragma unroll
    for (int r = 0; r < 8; ++r)
        out[(size_t)(row0 + r) * 64 + lane] = (unsigned short)bf16_rne(acc[r]);
}

// ---------------- fused aggregation, float4-quad form ----------------
template <int OUT_BF16>
__global__ void agg_v4(const int* __restrict__ rowp, const int* __restrict__ deg,
                       const int* __restrict__ col, const float* __restrict__ dinv,
                       const unsigned short* __restrict__ tab, const float* __restrict__ bias,
                       void* __restrict__ outv, int do_relu) {
    int wv = __builtin_amdgcn_readfirstlane(threadIdx.x >> 6);
    int node = blockIdx.x * 4 + wv;
    int lane = threadIdx.x & 63;
    int q = lane >> 4;
    int c4 = (lane & 15) << 2;
    float dd = dinv[node];
    int cnt = deg[node];
    int start = rowp[node];
    float4 acc = make_float4(0.f, 0.f, 0.f, 0.f);
    if (q == 0) {
        float4 xs = ldtab(tab, node, c4);
        float dd2 = dd * dd;
        acc.x = xs.x * dd2; acc.y = xs.y * dd2; acc.z = xs.z * dd2; acc.w = xs.w * dd2;
    }
    int j = 0;
    for (; j + 8 <= cnt; j += 8) {
        int sA = col[start + j + q];
        int sB = col[start + j + 4 + q];
        float nA = dinv[sA] * dd;
        float nB = dinv[sB] * dd;
        float4 xA = ldtab(tab, sA, c4);
        float4 xB = ldtab(tab, sB, c4);
        acc.x = fmaf(nA, xA.x, acc.x); acc.y = fmaf(nA, xA.y, acc.y);
        acc.z = fmaf(nA, xA.z, acc.z); acc.w = fmaf(nA, xA.w, acc.w);
        acc.x = fmaf(nB, xB.x, acc.x); acc.y = fmaf(nB, xB.y, acc.y);
        acc.z = fmaf(nB, xB.z, acc.z); acc.w = fmaf(nB, xB.w, acc.w);
    }
    for (; j < cnt; j += 4) {
        int jj = j + q;
        bool valid = jj < cnt;
        int s = col[start + (valid ? jj : 0)];
        float nv = valid ? dinv[s] * dd : 0.0f;
        float4 xv = ldtab(tab, s, c4);
        acc.x = fmaf(nv, xv.x, acc.x); acc.y = fmaf(nv, xv.y, acc.y);
        acc.z = fmaf(nv, xv.z, acc.z); acc.w = fmaf(nv, xv.w, acc.w);
    }
    acc.x += __shfl_xor(acc.x, 16); acc.y += __shfl_xor(acc.y, 16);
    acc.z += __shfl_xor(acc.z, 16); acc.w += __shfl_xor(acc.w, 16);
    acc.x += __shfl_xor(acc.x, 32); acc.y += __shfl_xor(acc.y, 32);
    acc.z += __shfl_xor(acc.z, 32); acc.w += __shfl_xor(acc.w, 32);
    if (q == 0) {
        if (bias) {
            float4 bv = *(const float4*)&bias[c4];
            acc.x += bv.x; acc.y += bv.y; acc.z += bv.z; acc.w += bv.w;
        }
        if (do_relu) {
            acc.x = fmaxf(acc.x, 0.f); acc.y = fmaxf(acc.y, 0.f);
            acc.z = fmaxf(acc.z, 0.f); acc.w = fmaxf(acc.w, 0.f);
        }
        if (OUT_BF16) {
            uint2 o;
            o.x = bf16_rne(acc.x) | (bf16_rne(acc.y) << 16);
            o.y = bf16_rne(acc.z) | (bf16_rne(acc.w) << 16);
            *(uint2*)&((unsigned short*)outv)[((size_t)node << 6) + c4] = o;
        } else {
            *(float4*)&((float*)outv)[((size_t)node << 6) + c4] = acc;
        }
    }
}

// ---------------- pool (+ per-graph node count): run-segmented, batch sorted ----------------
__global__ void pool_seg(const float* __restrict__ h, const int* __restrict__ batch,
                         float* __restrict__ pool, float* __restrict__ cntg) {
    int ch = threadIdx.x & 63;
    int grp = threadIdx.x >> 6;
    int base = (blockIdx.x * 4 + grp) * 16;
    float acc = 0.0f;
    int curg = -1, runlen = 0;
    for (int n = 0; n < 16; ++n) {
        int node = base + n;
        if (node >= N_NODES) break;
        int g = batch[node];
        float v = h[((size_t)node << 6) + ch];
        if (g != curg) {
            if (curg >= 0) {
                atomicAdd(&pool[curg * 64 + ch], acc);
                if (ch == 0) atomicAdd(&cntg[curg], (float)runlen);
            }
            curg = g; acc = v; runlen = 1;
        } else { acc += v; runlen++; }
    }
    if (curg >= 0) {
        atomicAdd(&pool[curg * 64 + ch], acc);
        if (ch == 0) atomicAdd(&cntg[curg], (float)runlen);
    }
}

// ---------------- tiny output GEMM: out = P @ W3 + cnt_g * b3 ----------------
__global__ void out_gemm(const float* __restrict__ P, const float* __restrict__ cntg,
                         const float* __restrict__ W, const float* __restrict__ b,
                         float* __restrict__ out) {
    __shared__ float Ws[64 * 64];
    int tid = threadIdx.x;
    for (int i = tid; i < 64 * 64; i += 256) Ws[i] = W[i];
    __syncthreads();
    int lane = tid & 63;
    int g = blockIdx.x * 4 + (tid >> 6);
    if (g >= N_GRAPHS) return;
    float pv = P[g * 64 + lane];
    float acc = 0.0f;
#pragma unroll
    for (int k = 0; k < 64; ++k)
        acc = fmaf(__shfl(pv, k, 64), Ws[k * 64 + lane], acc);
    out[g * 64 + lane] = acc + cntg[g] * b[lane];
}

extern "C" void kernel_launch(void* const* d_in, const int* in_sizes, int n_in,
                              void* d_out, int out_size, void* d_ws, size_t ws_size,
                              hipStream_t stream) {
    const float* x   = (const float*)d_in[0];
    const int* ei    = (const int*)d_in[1];   // int32 [2, N_EDGES]
    const int* batch = (const int*)d_in[2];   // int32 [N_NODES]
    const float* W1  = (const float*)d_in[3];
    const float* b1  = (const float*)d_in[4];
    const float* W2  = (const float*)d_in[5];
    const float* b2  = (const float*)d_in[6];
    const float* W3  = (const float*)d_in[7];
    const float* b3  = (const float*)d_in[8];
    float* out = (float*)d_out;

    // workspace layout (bytes), total ~29.5MB
    char* ws = (char*)d_ws;
    float* dinv  = (float*)(ws);                    // 50000 f32
    int*   DEG   = (int*)(ws + 200192);             // 50048 i32
    int*   ROWP  = (int*)(ws + 400384);             // 50000 i32
    int*   COL   = (int*)(ws + 600576);             // 800000 i32
    float* XW    = (float*)(ws + 3801600);          // 12.8MB; first 6.4MB doubles as EBUF
    int2*  EBUF  = (int2*)(ws + 3801600);           // 800000 int2 (dead after csr_bucket)
    float* ACC   = (float*)(ws + 16601600);         // 12.8MB
    float* POOL  = (float*)(ws + 29401600);         // 16384 f32
    float* CNT   = (float*)(ws + 29467136);         // 256 f32 (contiguous after POOL)
    int*   GHIST = (int*)(ws + 29468160);           // 196 i32
    int*   BST   = (int*)(ws + 29469184);           // 197 i32
    int*   GCUR  = (int*)(ws + 29470208);           // 196 i32

    const int WAVE_NODE_BLK = N_NODES / 4;          // 12500 (exact)
    const int GEMM_BLK = (N_NODES + 31) / 32;       // 1563
    const int SCAT_BLK = (N_EDGES + CHUNK - 1) / CHUNK;   // 98

    // ---- CSR build via 2-level counting sort (line-dense writes)
    zero_ghist<<<1, 256, 0, stream>>>(GHIST);
    edge_hist<<<128, 256, 0, stream>>>(ei, GHIST);
    bucket_scan<<<65, 256, 0, stream>>>(GHIST, BST, GCUR, POOL);
    bin_scatter<<<SCAT_BLK, 512, 0, stream>>>(ei, GCUR, EBUF);
    csr_bucket<<<NBUCK, 256, 0, stream>>>(EBUF, BST, DEG, ROWP, dinv, COL);

    // ---- layer 1: x -> XW(bf16) -> H1(f32) in ACC
    gemm_reg<<<GEMM_BLK, 256, 0, stream>>>(x, W1, (unsigned short*)XW, N_NODES);
    agg_v4<0><<<WAVE_NODE_BLK, 256, 0, stream>>>(ROWP, DEG, COL, dinv,
        (const unsigned short*)XW, b1, ACC, 1);

    // ---- layer 2: H1 -> XW(bf16) -> H2(bf16) in ACC
    gemm_reg<<<GEMM_BLK, 256, 0, stream>>>(ACC, W2, (unsigned short*)XW, N_NODES);
    agg_v4<1><<<WAVE_NODE_BLK, 256, 0, stream>>>(ROWP, DEG, COL, dinv,
        (const unsigned short*)XW, b2, ACC, 1);

    // ---- layer 3 (reordered): Z = A_hat H2 (f32 in XW) -> pool -> small GEMM
    agg_v4<0><<<WAVE_NODE_BLK, 256, 0, stream>>>(ROWP, DEG, COL, dinv,
        (const unsigned short*)ACC, nullptr, XW, 0);
    pool_seg<<<(N_NODES + 63) / 64, 256, 0, stream>>>(XW, batch, POOL, CNT);
    out_gemm<<<N_GRAPHS / 4, 256, 0, stream>>>(POOL, CNT, W3, b3, out);
}

// Round 9
// 241.579 us; speedup vs baseline: 3.7260x; 1.0420x over previous
//
#include <hip/hip_runtime.h>
#include <hip/hip_bf16.h>

#define N_NODES 50000
#define N_EDGES 800000
#define CH 64
#define N_GRAPHS 256
#define NBUCK 196            // ceil(50000/256); bucket = dst >> 8
#define CHUNK 4096           // edges staged per bin_scatter block
#define NHIST 98             // edge_hist blocks (partial histograms)

__device__ __forceinline__ unsigned bf16_rne(float f) {
    unsigned u = __float_as_uint(f);
    return (u + 0x7fffu + ((u >> 16) & 1u)) >> 16;
}
__device__ __forceinline__ float4 ldtab(const unsigned short* __restrict__ tab, int s, int c4) {
    uint2 u = *(const uint2*)(tab + ((size_t)s << 6) + c4);
    float4 r;
    r.x = __uint_as_float(u.x << 16);
    r.y = __uint_as_float(u.x & 0xffff0000u);
    r.z = __uint_as_float(u.y << 16);
    r.w = __uint_as_float(u.y & 0xffff0000u);
    return r;
}

// ---------------- pass A: per-block partial histograms (no zero kernel, no global atomics) ----
__global__ void edge_hist(const int* __restrict__ ei, int* __restrict__ hpart) {
    __shared__ int h[NBUCK];
    for (int i = threadIdx.x; i < NBUCK; i += 256) h[i] = 0;
    __syncthreads();
    int t = blockIdx.x * 256 + threadIdx.x;
    int stride = NHIST * 256 * 4;
    for (int e = t * 4; e < N_EDGES; e += stride) {
        int4 d = *(const int4*)&ei[N_EDGES + e];
        atomicAdd(&h[d.x >> 8], 1);
        atomicAdd(&h[d.y >> 8], 1);
        atomicAdd(&h[d.z >> 8], 1);
        atomicAdd(&h[d.w >> 8], 1);
    }
    __syncthreads();
    for (int i = threadIdx.x; i < NBUCK; i += 256)
        hpart[blockIdx.x * NBUCK + i] = h[i];
}

// ---------------- pass B: sum partials + bucket scan (+ POOL/CNT zero) ----------------
__global__ void bucket_scan(const int* __restrict__ hpart, int* __restrict__ bstart,
                            int* __restrict__ gcur, float* __restrict__ poolz) {
    int i = blockIdx.x * 256 + threadIdx.x;
    if (i < N_GRAPHS * CH + N_GRAPHS) poolz[i] = 0.0f;
    if (blockIdx.x != 0) return;
    __shared__ int sc[256];
    int tid = threadIdx.x;
    int v = 0;
    if (tid < NBUCK)
        for (int r = 0; r < NHIST; ++r) v += hpart[r * NBUCK + tid];
    sc[tid] = v;
    __syncthreads();
    for (int off = 1; off < 256; off <<= 1) {
        int t = (tid >= off) ? sc[tid - off] : 0;
        __syncthreads();
        sc[tid] += t;
        __syncthreads();
    }
    if (tid < NBUCK) {
        int ex = sc[tid] - v;
        bstart[tid] = ex;
        gcur[tid] = ex;
    }
    if (tid == 255) bstart[NBUCK] = sc[255];   // == N_EDGES
}

// ---------------- pass C: LDS-binned scatter into bucket-sorted EBUF ----------------
__global__ __launch_bounds__(512) void bin_scatter(const int* __restrict__ ei,
                                                   int* __restrict__ gcur,
                                                   int2* __restrict__ ebuf) {
    __shared__ int hist[NBUCK];
    __shared__ int lofs[NBUCK];
    __shared__ int gbase[NBUCK];
    __shared__ int cur[NBUCK];
    __shared__ int sc[512];
    __shared__ int2 stage[CHUNK];     // 32KB
    int tid = threadIdx.x;
    for (int i = tid; i < NBUCK; i += 512) hist[i] = 0;
    __syncthreads();
    int e0 = blockIdx.x * CHUNK;
    int n = min(CHUNK, N_EDGES - e0);
    int src[8], dst[8];
#pragma unroll
    for (int k = 0; k < 8; ++k) {
        int idx = k * 512 + tid;
        if (idx < n) {
            int e = e0 + idx;
            src[k] = ei[e];
            dst[k] = ei[N_EDGES + e];
            atomicAdd(&hist[dst[k] >> 8], 1);
        } else dst[k] = -1;
    }
    __syncthreads();
    int v = (tid < NBUCK) ? hist[tid] : 0;
    sc[tid] = v;
    __syncthreads();
    for (int off = 1; off < 512; off <<= 1) {
        int t = (tid >= off) ? sc[tid - off] : 0;
        __syncthreads();
        sc[tid] += t;
        __syncthreads();
    }
    if (tid < NBUCK) {
        int ex = sc[tid] - v;
        lofs[tid] = ex;
        cur[tid] = ex;
        gbase[tid] = v ? atomicAdd(&gcur[tid], v) : 0;
    }
    __syncthreads();
#pragma unroll
    for (int k = 0; k < 8; ++k) {
        if (dst[k] >= 0) {
            int p = atomicAdd(&cur[dst[k] >> 8], 1);
            stage[p] = make_int2(src[k], dst[k]);
        }
    }
    __syncthreads();
    for (int i = tid; i < n; i += 512) {
        int2 p = stage[i];
        int b = p.y >> 8;
        ebuf[gbase[b] + (i - lofs[b])] = p;     // contiguous runs per bucket
    }
}

// ---------------- pass D: per-bucket CSR build (deg, rowp, dinv, col) ----------------
__global__ void csr_bucket(const int2* __restrict__ ebuf, const int* __restrict__ bstart,
                           int* __restrict__ deg, int* __restrict__ rowp,
                           float* __restrict__ dinv, int* __restrict__ col) {
    __shared__ int nd[256];
    __shared__ int cur[256];
    __shared__ int sc[256];
    int b = blockIdx.x;
    int tid = threadIdx.x;
    nd[tid] = 0;
    __syncthreads();
    int es = bstart[b], ee = bstart[b + 1];
    for (int e = es + tid; e < ee; e += 256)
        atomicAdd(&nd[ebuf[e].y & 255], 1);
    __syncthreads();
    int v = nd[tid];
    sc[tid] = v;
    __syncthreads();
    for (int off = 1; off < 256; off <<= 1) {
        int t = (tid >= off) ? sc[tid - off] : 0;
        __syncthreads();
        sc[tid] += t;
        __syncthreads();
    }
    int node = b * 256 + tid;
    int lstart = es + sc[tid] - v;
    if (node < N_NODES) {
        deg[node] = v;
        rowp[node] = lstart;
        dinv[node] = rsqrtf((float)v + 1.0f);
    }
    cur[tid] = lstart;
    __syncthreads();
    for (int e = es + tid; e < ee; e += 256) {
        int2 p = ebuf[e];
        int pos = atomicAdd(&cur[p.y & 255], 1);
        col[pos] = p.x;
    }
}

// ---------------- register-blocked GEMM -> bf16 out ----------------
__global__ void gemm_reg(const float* __restrict__ in, const float* __restrict__ W,
                         unsigned short* __restrict__ out, int n) {
    __shared__ float WT[64 * 68];
    int tid = threadIdx.x;
    for (int i = tid; i < 64 * 64; i += 256) {
        int k = i >> 6, c = i & 63;
        WT[c * 68 + k] = W[i];
    }
    __syncthreads();
    int lane = tid & 63;
    int wv = __builtin_amdgcn_readfirstlane(tid >> 6);
    int row0 = blockIdx.x * 32 + wv * 8;
    if (row0 >= n) return;
    float acc[8] = {0.f, 0.f, 0.f, 0.f, 0.f, 0.f, 0.f, 0.f};
#pragma unroll 2
    for (int k = 0; k < 64; k += 4) {
        float4 w = *(const float4*)&WT[lane * 68 + k];
#pragma unroll
        for (int r = 0; r < 8; ++r) {
            float4 xv = *(const float4*)&in[(size_t)(row0 + r) * 64 + k];  // scalar load
            acc[r] = fmaf(xv.x, w.x, acc[r]);
            acc[r] = fmaf(xv.y, w.y, acc[r]);
            acc[r] = fmaf(xv.z, w.z, acc[r]);
            acc[r] = fmaf(xv.w, w.w, acc[r]);
        }
    }
#pragma unroll
    for (int r = 0; r < 8; ++r)
        out[(size_t)(row0 + r) * 64 + lane] = (unsigned short)bf16_rne(acc[r]);
}

// ---------------- fused aggregation, float4-quad form ----------------
// wave = 1 node; lane l: edge slot q=l>>4, channel quad c4=(l&15)*4
// WRITE_NRM: layer 1 caches per-edge norms; USE_NRM: layers 2-3 stream them back
template <int OUT_BF16, int USE_NRM, int WRITE_NRM>
__global__ void agg_v4(const int* __restrict__ rowp, const int* __restrict__ deg,
                       const int* __restrict__ col, const float* __restrict__ dinv,
                       float* nrm,
                       const unsigned short* __restrict__ tab, const float* __restrict__ bias,
                       void* __restrict__ outv, int do_relu) {
    int wv = __builtin_amdgcn_readfirstlane(threadIdx.x >> 6);
    int node = blockIdx.x * 4 + wv;
    int lane = threadIdx.x & 63;
    int q = lane >> 4;
    int c4 = (lane & 15) << 2;
    float dd = dinv[node];
    int cnt = deg[node];
    int start = rowp[node];
    float4 acc = make_float4(0.f, 0.f, 0.f, 0.f);
    if (q == 0) {
        float4 xs = ldtab(tab, node, c4);
        float dd2 = dd * dd;
        acc.x = xs.x * dd2; acc.y = xs.y * dd2; acc.z = xs.z * dd2; acc.w = xs.w * dd2;
    }
    int j = 0;
    for (; j + 8 <= cnt; j += 8) {
        int sA = col[start + j + q];
        int sB = col[start + j + 4 + q];
        float nA, nB;
        if (USE_NRM) {
            nA = nrm[start + j + q];
            nB = nrm[start + j + 4 + q];
        } else {
            nA = dinv[sA] * dd;
            nB = dinv[sB] * dd;
        }
        float4 xA = ldtab(tab, sA, c4);
        float4 xB = ldtab(tab, sB, c4);
        if (WRITE_NRM && (lane & 15) == 0) {
            nrm[start + j + q] = nA;
            nrm[start + j + 4 + q] = nB;
        }
        acc.x = fmaf(nA, xA.x, acc.x); acc.y = fmaf(nA, xA.y, acc.y);
        acc.z = fmaf(nA, xA.z, acc.z); acc.w = fmaf(nA, xA.w, acc.w);
        acc.x = fmaf(nB, xB.x, acc.x); acc.y = fmaf(nB, xB.y, acc.y);
        acc.z = fmaf(nB, xB.z, acc.z); acc.w = fmaf(nB, xB.w, acc.w);
    }
    for (; j < cnt; j += 4) {
        int jj = j + q;
        bool valid = jj < cnt;
        int s = col[start + (valid ? jj : 0)];
        float nv;
        if (USE_NRM) {
            nv = valid ? nrm[start + jj] : 0.0f;
        } else {
            nv = valid ? dinv[s] * dd : 0.0f;
        }
        if (WRITE_NRM && valid && (lane & 15) == 0) nrm[start + jj] = nv;
        float4 xv = ldtab(tab, s, c4);
        acc.x = fmaf(nv, xv.x, acc.x); acc.y = fmaf(nv, xv.y, acc.y);
        acc.z = fmaf(nv, xv.z, acc.z); acc.w = fmaf(nv, xv.w, acc.w);
    }
    acc.x += __shfl_xor(acc.x, 16); acc.y += __shfl_xor(acc.y, 16);
    acc.z += __shfl_xor(acc.z, 16); acc.w += __shfl_xor(acc.w, 16);
    acc.x += __shfl_xor(acc.x, 32); acc.y += __shfl_xor(acc.y, 32);
    acc.z += __shfl_xor(acc.z, 32); acc.w += __shfl_xor(acc.w, 32);
    if (q == 0) {
        if (bias) {
            float4 bv = *(const float4*)&bias[c4];
            acc.x += bv.x; acc.y += bv.y; acc.z += bv.z; acc.w += bv.w;
        }
        if (do_relu) {
            acc.x = fmaxf(acc.x, 0.f); acc.y = fmaxf(acc.y, 0.f);
            acc.z = fmaxf(acc.z, 0.f); acc.w = fmaxf(acc.w, 0.f);
        }
        if (OUT_BF16) {
            uint2 o;
            o.x = bf16_rne(acc.x) | (bf16_rne(acc.y) << 16);
            o.y = bf16_rne(acc.z) | (bf16_rne(acc.w) << 16);
            *(uint2*)&((unsigned short*)outv)[((size_t)node << 6) + c4] = o;
        } else {
            *(float4*)&((float*)outv)[((size_t)node << 6) + c4] = acc;
        }
    }
}

// ---------------- pool (+ per-graph node count): run-segmented, batch sorted ----------------
__global__ void pool_seg(const float* __restrict__ h, const int* __restrict__ batch,
                         float* __restrict__ pool, float* __restrict__ cntg) {
    int ch = threadIdx.x & 63;
    int grp = threadIdx.x >> 6;
    int base = (blockIdx.x * 4 + grp) * 16;
    float acc = 0.0f;
    int curg = -1, runlen = 0;
    for (int n = 0; n < 16; ++n) {
        int node = base + n;
        if (node >= N_NODES) break;
        int g = batch[node];
        float v = h[((size_t)node << 6) + ch];
        if (g != curg) {
            if (curg >= 0) {
                atomicAdd(&pool[curg * 64 + ch], acc);
                if (ch == 0) atomicAdd(&cntg[curg], (float)runlen);
            }
            curg = g; acc = v; runlen = 1;
        } else { acc += v; runlen++; }
    }
    if (curg >= 0) {
        atomicAdd(&pool[curg * 64 + ch], acc);
        if (ch == 0) atomicAdd(&cntg[curg], (float)runlen);
    }
}

// ---------------- tiny output GEMM: out = P @ W3 + cnt_g * b3 ----------------
__global__ void out_gemm(const float* __restrict__ P, const float* __restrict__ cntg,
                         const float* __restrict__ W, const float* __restrict__ b,
                         float* __restrict__ out) {
    __shared__ float Ws[64 * 64];
    int tid = threadIdx.x;
    for (int i = tid; i < 64 * 64; i += 256) Ws[i] = W[i];
    __syncthreads();
    int lane = tid & 63;
    int g = blockIdx.x * 4 + (tid >> 6);
    if (g >= N_GRAPHS) return;
    float pv = P[g * 64 + lane];
    float acc = 0.0f;
#pragma unroll
    for (int k = 0; k < 64; ++k)
        acc = fmaf(__shfl(pv, k, 64), Ws[k * 64 + lane], acc);
    out[g * 64 + lane] = acc + cntg[g] * b[lane];
}

extern "C" void kernel_launch(void* const* d_in, const int* in_sizes, int n_in,
                              void* d_out, int out_size, void* d_ws, size_t ws_size,
                              hipStream_t stream) {
    const float* x   = (const float*)d_in[0];
    const int* ei    = (const int*)d_in[1];   // int32 [2, N_EDGES]
    const int* batch = (const int*)d_in[2];   // int32 [N_NODES]
    const float* W1  = (const float*)d_in[3];
    const float* b1  = (const float*)d_in[4];
    const float* W2  = (const float*)d_in[5];
    const float* b2  = (const float*)d_in[6];
    const float* W3  = (const float*)d_in[7];
    const float* b3  = (const float*)d_in[8];
    float* out = (float*)d_out;

    // workspace layout (bytes), total ~32.8MB
    char* ws = (char*)d_ws;
    float* dinv  = (float*)(ws);                    // 50000 f32
    int*   DEG   = (int*)(ws + 200192);             // 50048 i32
    int*   ROWP  = (int*)(ws + 400384);             // 50000 i32
    int*   COL   = (int*)(ws + 600576);             // 800000 i32
    float* NRM   = (float*)(ws + 3800576);          // 800000 f32 (per-edge norms)
    int*   HPART = (int*)(ws + 7000576);            // 98*196 i32 partial hists
    int*   BST   = (int*)(ws + 7077888);            // 197 i32
    int*   GCUR  = (int*)(ws + 7078912);            // 196 i32
    float* XW    = (float*)(ws + 7080960);          // 12.8MB; first 6.4MB doubles as EBUF
    int2*  EBUF  = (int2*)(ws + 7080960);           // 800000 int2 (dead after csr_bucket)
    float* ACC   = (float*)(ws + 19880960);         // 12.8MB
    float* POOL  = (float*)(ws + 32680960);         // 16384 f32
    float* CNT   = (float*)(ws + 32746496);         // 256 f32 (contiguous after POOL)

    const int WAVE_NODE_BLK = N_NODES / 4;          // 12500 (exact)
    const int GEMM_BLK = (N_NODES + 31) / 32;       // 1563
    const int SCAT_BLK = (N_EDGES + CHUNK - 1) / CHUNK;   // 196

    // ---- CSR build via 2-level counting sort (line-dense writes)
    edge_hist<<<NHIST, 256, 0, stream>>>(ei, HPART);
    bucket_scan<<<65, 256, 0, stream>>>(HPART, BST, GCUR, POOL);
    bin_scatter<<<SCAT_BLK, 512, 0, stream>>>(ei, GCUR, EBUF);
    csr_bucket<<<NBUCK, 256, 0, stream>>>(EBUF, BST, DEG, ROWP, dinv, COL);

    // ---- layer 1: x -> XW(bf16) -> H1(f32) in ACC; caches NRM
    gemm_reg<<<GEMM_BLK, 256, 0, stream>>>(x, W1, (unsigned short*)XW, N_NODES);
    agg_v4<0, 0, 1><<<WAVE_NODE_BLK, 256, 0, stream>>>(ROWP, DEG, COL, dinv, NRM,
        (const unsigned short*)XW, b1, ACC, 1);

    // ---- layer 2: H1 -> XW(bf16) -> H2(bf16) in ACC; streams NRM
    gemm_reg<<<GEMM_BLK, 256, 0, stream>>>(ACC, W2, (unsigned short*)XW, N_NODES);
    agg_v4<1, 1, 0><<<WAVE_NODE_BLK, 256, 0, stream>>>(ROWP, DEG, COL, dinv, NRM,
        (const unsigned short*)XW, b2, ACC, 1);

    // ---- layer 3 (reordered): Z = A_hat H2 (f32 in XW) -> pool -> small GEMM
    agg_v4<0, 1, 0><<<WAVE_NODE_BLK, 256, 0, stream>>>(ROWP, DEG, COL, dinv, NRM,
        (const unsigned short*)ACC, nullptr, XW, 0);
    pool_seg<<<(N_NODES + 63) / 64, 256, 0, stream>>>(XW, batch, POOL, CNT);
    out_gemm<<<N_GRAPHS / 4, 256, 0, stream>>>(POOL, CNT, W3, b3, out);
}